// Round 8
// baseline (12510.451 us; speedup 1.0000x reference)
//
#include <hip/hip_runtime.h>

// Problem constants (fixed shapes from reference)
constexpr int S   = 4096;   // sequence length
constexpr int H   = 512;    // hidden
constexpr int G3  = 1536;   // 3*H
constexpr int NWG = 32;     // scan worker workgroups; each owns H/NWG = 16 hidden idx
constexpr int GXW = 32;     // gx staging window (steps)

// ---------------------------------------------------------------------------
// Kernel A: gx[t][o] = b_ih[o] + sum_k emb[x[t]][k] * w_ih[o][k]
// (unchanged — passed with absmax 0.0; ~1% of runtime)
// ---------------------------------------------------------------------------
__global__ __launch_bounds__(256) void gemm_gx(
    const int* __restrict__ x, const float* __restrict__ emb,
    const float* __restrict__ w_ih, const float* __restrict__ b_ih,
    float* __restrict__ gx)
{
    __shared__ alignas(16) float As[128][36];
    __shared__ alignas(16) float Bs[32][132];

    const int tid  = threadIdx.x;
    const int row0 = (blockIdx.x / 12) * 128;
    const int col0 = (blockIdx.x % 12) * 128;
    const int tx   = tid & 15;
    const int ty   = tid >> 4;

    float acc[8][8] = {};

    for (int k0 = 0; k0 < H; k0 += 32) {
        #pragma unroll
        for (int p = 0; p < 4; ++p) {
            const int rl = (tid >> 3) + 32 * p;
            const int kk = (tid & 7) * 4;
            const int xi = x[row0 + rl];
            const float4 va = *reinterpret_cast<const float4*>(
                emb + (size_t)xi * H + k0 + kk);
            *reinterpret_cast<float4*>(&As[rl][kk]) = va;

            const float4 vb = *reinterpret_cast<const float4*>(
                w_ih + (size_t)(col0 + rl) * H + k0 + kk);
            Bs[kk + 0][rl] = vb.x; Bs[kk + 1][rl] = vb.y;
            Bs[kk + 2][rl] = vb.z; Bs[kk + 3][rl] = vb.w;
        }
        __syncthreads();

        #pragma unroll
        for (int kk = 0; kk < 32; ++kk) {
            float a[8], b[8];
            #pragma unroll
            for (int q = 0; q < 4; ++q) {
                a[q]     = As[ty * 4 + q][kk];
                a[4 + q] = As[ty * 4 + 64 + q][kk];
            }
            const float4 b0 = *reinterpret_cast<const float4*>(&Bs[kk][tx * 4]);
            const float4 b1 = *reinterpret_cast<const float4*>(&Bs[kk][tx * 4 + 64]);
            b[0]=b0.x; b[1]=b0.y; b[2]=b0.z; b[3]=b0.w;
            b[4]=b1.x; b[5]=b1.y; b[6]=b1.z; b[7]=b1.w;
            #pragma unroll
            for (int ri = 0; ri < 8; ++ri)
                #pragma unroll
                for (int ci = 0; ci < 8; ++ci)
                    acc[ri][ci] = fmaf(a[ri], b[ci], acc[ri][ci]);
        }
        __syncthreads();
    }

    float bi[8];
    #pragma unroll
    for (int q = 0; q < 4; ++q) {
        bi[q]     = b_ih[col0 + tx * 4 + q];
        bi[4 + q] = b_ih[col0 + tx * 4 + 64 + q];
    }
    #pragma unroll
    for (int ri = 0; ri < 8; ++ri) {
        const int rr = row0 + ty * 4 + (ri & 3) + ((ri >> 2) << 6);
        float4 o0, o1;
        o0.x = acc[ri][0] + bi[0]; o0.y = acc[ri][1] + bi[1];
        o0.z = acc[ri][2] + bi[2]; o0.w = acc[ri][3] + bi[3];
        o1.x = acc[ri][4] + bi[4]; o1.y = acc[ri][5] + bi[5];
        o1.z = acc[ri][6] + bi[6]; o1.w = acc[ri][7] + bi[7];
        *reinterpret_cast<float4*>(gx + (size_t)rr * G3 + col0 + tx * 4)      = o0;
        *reinterpret_cast<float4*>(gx + (size_t)rr * G3 + col0 + tx * 4 + 64) = o1;
    }
}

// ---------------------------------------------------------------------------
// Kernel B: persistent GRU scan — WAVE-AUTONOMOUS, ZERO in-loop barriers.
// Sync protocol unchanged (rounds 1/3/7, all passed): tag-in-data u64
// (tag<<32|f32), double-buffered hbuf[2][H], relaxed agent-scope atomic
// stores, tag-gated consumption.
// Structure:
//   - 32 WGs x 256 thr; WG k owns rows [16k,16k+16). Wave w' (4 per WG) owns
//     rows 16k+4w'..+3 and is fully autonomous: it polls ALL 512 slots itself
//     (each lane: 4 pipelined dwordx4 sc0 sc1 = 64B, one vmcnt(0) -> whole-
//     state sample per RTT), fills its PRIVATE LDS h copy, computes its 4
//     rows, stores. No s_barrier => no cross-wave jitter coupling.
//   - gx bulk-staged per wave every 32 steps (384 scalars) => ZERO per-step
//     global loads besides the poll; round 7's cold gx HBM loads sat in the
//     wave's vmcnt FIFO and (in-order retire, m135) delayed the first poll
//     sample of every step by up to ~375ns.
//   - Overwrite safety at wave granularity: all 512 tags@s+1 => all 128
//     waves stored, which requires each to have consumed ALL of h_s =>
//     buffer (s&1) is dead => safe for h_{s+2}.
// ---------------------------------------------------------------------------
__global__ __launch_bounds__(256, 1) void gru_scan(
    const float* __restrict__ gx,
    const float* __restrict__ w_hh,
    const float* __restrict__ b_hh,
    const float* __restrict__ dec_w,
    const float* __restrict__ dec_b,
    const float* __restrict__ target,
    unsigned long long* __restrict__ hbuf,   // [2][H] (tag|value)
    float* __restrict__ out)
{
    __shared__ alignas(16) float hw[4][H];          // per-wave h copy (8 KB)
    __shared__ alignas(16) float gxw[4][GXW * 12];  // per-wave gx window (6 KB)

    const int tid  = threadIdx.x;
    const int wv   = tid >> 6;       // wave id 0..3
    const int lane = tid & 63;
    const int k    = blockIdx.x;
    const int g    = tid >> 4;       // group id 0..15 (16 lanes per group)
    const int l    = tid & 15;       // lane within group (column owner)
    const int r    = g & 3;          // row-within-wave 0..3
    const int i    = k * 16 + g;     // owned hidden index (group's output row)
    const int row_base = k * 16 + (wv << 2);   // first row owned by this wave

    // Recurrent weights: rows i, H+i, 2H+i; cols 4l+64j+q (round-7 layout).
    float4 wr[8], wz[8], wn[8];
    #pragma unroll
    for (int j = 0; j < 8; ++j) {
        const int c = 4 * l + 64 * j;
        wr[j] = *reinterpret_cast<const float4*>(w_hh + (size_t)i * H + c);
        wz[j] = *reinterpret_cast<const float4*>(w_hh + (size_t)(H + i) * H + c);
        wn[j] = *reinterpret_cast<const float4*>(w_hh + (size_t)(2 * H + i) * H + c);
    }
    const float bhr = b_hh[i], bhz = b_hh[H + i], bhn = b_hh[2 * H + i];

    float* hl  = hw[wv];
    float* gxl = gxw[wv];

    for (int s = 0; s < S; ++s) {
        // --- 1) obtain full h_s into this wave's LDS copy ---
        if (s == 0) {
            const float4 z4 = make_float4(0.f, 0.f, 0.f, 0.f);
            *reinterpret_cast<float4*>(&hl[8 * lane])     = z4;
            *reinterpret_cast<float4*>(&hl[8 * lane + 4]) = z4;
        } else {
            const unsigned tg = (unsigned)s;
            const char* base =
                (const char*)(hbuf + (size_t)(s & 1) * H) + 64 * (size_t)lane;
            uint4 a, b, c, d;
            while (true) {
                asm volatile(
                    "global_load_dwordx4 %0, %4, off sc0 sc1\n\t"
                    "global_load_dwordx4 %1, %5, off sc0 sc1\n\t"
                    "global_load_dwordx4 %2, %6, off sc0 sc1\n\t"
                    "global_load_dwordx4 %3, %7, off sc0 sc1\n\t"
                    "s_waitcnt vmcnt(0)"
                    : "=&v"(a), "=&v"(b), "=&v"(c), "=&v"(d)
                    : "v"(base), "v"(base + 16), "v"(base + 32), "v"(base + 48)
                    : "memory");
                if (a.y == tg && a.w == tg && b.y == tg && b.w == tg &&
                    c.y == tg && c.w == tg && d.y == tg && d.w == tg) break;
            }
            float4 v0, v1;
            v0.x = __uint_as_float(a.x); v0.y = __uint_as_float(a.z);
            v0.z = __uint_as_float(b.x); v0.w = __uint_as_float(b.z);
            v1.x = __uint_as_float(c.x); v1.y = __uint_as_float(c.z);
            v1.z = __uint_as_float(d.x); v1.w = __uint_as_float(d.z);
            *reinterpret_cast<float4*>(&hl[8 * lane])     = v0;
            *reinterpret_cast<float4*>(&hl[8 * lane + 4]) = v1;
        }

        // --- 2) bulk-stage gx window every GXW steps (per-wave, no barrier) ---
        if ((s & (GXW - 1)) == 0) {
            float tmp[6];
            #pragma unroll
            for (int m = 0; m < 6; ++m) {
                const int idx = lane + 64 * m;          // 0..383
                const int tr  = idx / 12;
                const int rem = idx % 12;
                const int q   = rem >> 2;
                const int rr  = rem & 3;
                tmp[m] = gx[(size_t)(s + tr) * G3 + q * H + row_base + rr];
            }
            #pragma unroll
            for (int m = 0; m < 6; ++m) gxl[lane + 64 * m] = tmp[m];
        }

        // order own-wave LDS writes before reads (no cross-wave sharing)
        __builtin_amdgcn_sched_barrier(0);
        asm volatile("s_waitcnt lgkmcnt(0)" ::: "memory");
        __builtin_amdgcn_sched_barrier(0);

        const float hp = hl[i];

        // --- 3) three 512-dots: lane l covers cols 4l+64j via ds_read_b128 ---
        float ar = 0.f, az = 0.f, an = 0.f;
        #pragma unroll
        for (int j = 0; j < 8; ++j) {
            const float4 hv =
                *reinterpret_cast<const float4*>(&hl[64 * j + 4 * l]);
            ar = fmaf(wr[j].x, hv.x, fmaf(wr[j].y, hv.y,
                 fmaf(wr[j].z, hv.z, fmaf(wr[j].w, hv.w, ar))));
            az = fmaf(wz[j].x, hv.x, fmaf(wz[j].y, hv.y,
                 fmaf(wz[j].z, hv.z, fmaf(wz[j].w, hv.w, az))));
            an = fmaf(wn[j].x, hv.x, fmaf(wn[j].y, hv.y,
                 fmaf(wn[j].z, hv.z, fmaf(wn[j].w, hv.w, an))));
        }
        #pragma unroll
        for (int m = 8; m >= 1; m >>= 1) {   // butterfly within 16-lane group
            ar += __shfl_xor(ar, m);
            az += __shfl_xor(az, m);
            an += __shfl_xor(an, m);
        }

        // --- 4) gates + publish (lane 0 of each group) ---
        if (l == 0) {
            const int sl = s & (GXW - 1);
            const float gxr = gxl[sl * 12 + r];
            const float gxz = gxl[sl * 12 + 4 + r];
            const float gxn = gxl[sl * 12 + 8 + r];
            const float rr  = 1.f / (1.f + __expf(-(gxr + ar + bhr)));
            const float zz  = 1.f / (1.f + __expf(-(gxz + az + bhz)));
            const float nn  = tanhf(gxn + rr * (an + bhn));
            const float hnew = (1.f - zz) * nn + zz * hp;
            const unsigned long long pv =
                ((unsigned long long)(unsigned)(s + 1) << 32) |
                (unsigned long long)__float_as_uint(hnew);
            __hip_atomic_store(hbuf + (size_t)((s + 1) & 1) * H + i, pv,
                               __ATOMIC_RELAXED, __HIP_MEMORY_SCOPE_AGENT);
        }
        // no barrier: waves are autonomous; LDS regions are private per wave.
    }

    // --- epilogue: WG0 wave0 gathers h_S (tag S, buffer 0) and computes BCE ---
    if (k == 0 && wv == 0) {
        const unsigned tg = (unsigned)S;
        const char* base = (const char*)hbuf + 64 * (size_t)lane;
        uint4 a, b, c, d;
        while (true) {
            asm volatile(
                "global_load_dwordx4 %0, %4, off sc0 sc1\n\t"
                "global_load_dwordx4 %1, %5, off sc0 sc1\n\t"
                "global_load_dwordx4 %2, %6, off sc0 sc1\n\t"
                "global_load_dwordx4 %3, %7, off sc0 sc1\n\t"
                "s_waitcnt vmcnt(0)"
                : "=&v"(a), "=&v"(b), "=&v"(c), "=&v"(d)
                : "v"(base), "v"(base + 16), "v"(base + 32), "v"(base + 48)
                : "memory");
            if (a.y == tg && a.w == tg && b.y == tg && b.w == tg &&
                c.y == tg && c.w == tg && d.y == tg && d.w == tg) break;
        }
        const float h0 = __uint_as_float(a.x), h1 = __uint_as_float(a.z);
        const float h2 = __uint_as_float(b.x), h3 = __uint_as_float(b.z);
        const float h4 = __uint_as_float(c.x), h5 = __uint_as_float(c.z);
        const float h6 = __uint_as_float(d.x), h7 = __uint_as_float(d.z);
        const float* dw = dec_w + 8 * lane;
        float p = h0 * dw[0] + h1 * dw[1] + h2 * dw[2] + h3 * dw[3] +
                  h4 * dw[4] + h5 * dw[5] + h6 * dw[6] + h7 * dw[7];
        #pragma unroll
        for (int m = 32; m >= 1; m >>= 1) p += __shfl_xor(p, m);
        if (lane == 0) {
            const float xl = p + dec_b[0];
            const float t  = target[0];
            const float loss = fmaxf(xl, 0.f) - xl * t +
                               log1pf(__expf(-fabsf(xl)));
            out[0] = loss;
        }
    }
}

// ---------------------------------------------------------------------------
extern "C" void kernel_launch(void* const* d_in, const int* in_sizes, int n_in,
                              void* d_out, int out_size, void* d_ws, size_t ws_size,
                              hipStream_t stream) {
    const int*   x      = (const int*)d_in[0];
    const float* target = (const float*)d_in[1];
    const float* emb    = (const float*)d_in[2];
    const float* w_ih   = (const float*)d_in[3];
    const float* w_hh   = (const float*)d_in[4];
    const float* b_ih   = (const float*)d_in[5];
    const float* b_hh   = (const float*)d_in[6];
    const float* dec_w  = (const float*)d_in[7];
    const float* dec_b  = (const float*)d_in[8];
    float*       out    = (float*)d_out;

    float* gx = (float*)d_ws;                                   // [S][1536] = 25.2 MB
    unsigned long long* hbuf =
        (unsigned long long*)((char*)d_ws + (size_t)S * G3 * sizeof(float)); // [2][H]

    // Clear tags every launch so graph replays can't match stale tags.
    hipMemsetAsync(hbuf, 0, 2 * H * sizeof(unsigned long long), stream);

    gemm_gx<<<dim3(32 * 12), dim3(256), 0, stream>>>(x, emb, w_ih, b_ih, gx);
    gru_scan<<<dim3(NWG), dim3(256), 0, stream>>>(gx, w_hh, b_hh, dec_w, dec_b,
                                                  target, hbuf, out);
}

// Round 9
// 7190.741 us; speedup vs baseline: 1.7398x; 1.7398x over previous
//
#include <hip/hip_runtime.h>

// Problem constants (fixed shapes from reference)
constexpr int S   = 4096;   // sequence length
constexpr int H   = 512;    // hidden
constexpr int G3  = 1536;   // 3*H
constexpr int NWG = 16;     // scan worker WGs; each owns H/NWG = 32 hidden idx

// Single-slot poll load from the coherence point (sc0 = L1 bypass, sc1 = L2
// bypass -> MALL). One u64 (tag|value) per thread -> minimal sampling loop.
__device__ inline unsigned long long ld2_mall(const void* p) {
    unsigned long long v;
    asm volatile("global_load_dwordx2 %0, %1, off sc0 sc1\n\ts_waitcnt vmcnt(0)"
                 : "=v"(v) : "v"(p) : "memory");
    return v;
}

// LDS-only barrier: orders LDS ops across the WG without draining vmcnt
// (producer's MALL store + gx prefetches stay in flight). sched_barrier
// fences stop the compiler from moving LDS ops across (m214 rule 18).
__device__ inline void barrier_lds() {
    __builtin_amdgcn_sched_barrier(0);
    asm volatile("s_waitcnt lgkmcnt(0)" ::: "memory");
    __builtin_amdgcn_s_barrier();
    __builtin_amdgcn_sched_barrier(0);
}

// ---------------------------------------------------------------------------
// Kernel A: gx[t][o] = b_ih[o] + sum_k emb[x[t]][k] * w_ih[o][k]
// (unchanged — passed with absmax 0.0; ~1% of runtime)
// ---------------------------------------------------------------------------
__global__ __launch_bounds__(256) void gemm_gx(
    const int* __restrict__ x, const float* __restrict__ emb,
    const float* __restrict__ w_ih, const float* __restrict__ b_ih,
    float* __restrict__ gx)
{
    __shared__ alignas(16) float As[128][36];
    __shared__ alignas(16) float Bs[32][132];

    const int tid  = threadIdx.x;
    const int row0 = (blockIdx.x / 12) * 128;
    const int col0 = (blockIdx.x % 12) * 128;
    const int tx   = tid & 15;
    const int ty   = tid >> 4;

    float acc[8][8] = {};

    for (int k0 = 0; k0 < H; k0 += 32) {
        #pragma unroll
        for (int p = 0; p < 4; ++p) {
            const int rl = (tid >> 3) + 32 * p;
            const int kk = (tid & 7) * 4;
            const int xi = x[row0 + rl];
            const float4 va = *reinterpret_cast<const float4*>(
                emb + (size_t)xi * H + k0 + kk);
            *reinterpret_cast<float4*>(&As[rl][kk]) = va;

            const float4 vb = *reinterpret_cast<const float4*>(
                w_ih + (size_t)(col0 + rl) * H + k0 + kk);
            Bs[kk + 0][rl] = vb.x; Bs[kk + 1][rl] = vb.y;
            Bs[kk + 2][rl] = vb.z; Bs[kk + 3][rl] = vb.w;
        }
        __syncthreads();

        #pragma unroll
        for (int kk = 0; kk < 32; ++kk) {
            float a[8], b[8];
            #pragma unroll
            for (int q = 0; q < 4; ++q) {
                a[q]     = As[ty * 4 + q][kk];
                a[4 + q] = As[ty * 4 + 64 + q][kk];
            }
            const float4 b0 = *reinterpret_cast<const float4*>(&Bs[kk][tx * 4]);
            const float4 b1 = *reinterpret_cast<const float4*>(&Bs[kk][tx * 4 + 64]);
            b[0]=b0.x; b[1]=b0.y; b[2]=b0.z; b[3]=b0.w;
            b[4]=b1.x; b[5]=b1.y; b[6]=b1.z; b[7]=b1.w;
            #pragma unroll
            for (int ri = 0; ri < 8; ++ri)
                #pragma unroll
                for (int ci = 0; ci < 8; ++ci)
                    acc[ri][ci] = fmaf(a[ri], b[ci], acc[ri][ci]);
        }
        __syncthreads();
    }

    float bi[8];
    #pragma unroll
    for (int q = 0; q < 4; ++q) {
        bi[q]     = b_ih[col0 + tx * 4 + q];
        bi[4 + q] = b_ih[col0 + tx * 4 + 64 + q];
    }
    #pragma unroll
    for (int ri = 0; ri < 8; ++ri) {
        const int rr = row0 + ty * 4 + (ri & 3) + ((ri >> 2) << 6);
        float4 o0, o1;
        o0.x = acc[ri][0] + bi[0]; o0.y = acc[ri][1] + bi[1];
        o0.z = acc[ri][2] + bi[2]; o0.w = acc[ri][3] + bi[3];
        o1.x = acc[ri][4] + bi[4]; o1.y = acc[ri][5] + bi[5];
        o1.z = acc[ri][6] + bi[6]; o1.w = acc[ri][7] + bi[7];
        *reinterpret_cast<float4*>(gx + (size_t)rr * G3 + col0 + tx * 4)      = o0;
        *reinterpret_cast<float4*>(gx + (size_t)rr * G3 + col0 + tx * 4 + 64) = o1;
    }
}

// ---------------------------------------------------------------------------
// Kernel B: persistent GRU scan. 16 WGs x 512 threads (WG k owns rows
// [32k, 32k+32); 16-lane group g computes row i = 32k+g).
// Sync protocol = rounds 1/3/7 PROVEN: tag-in-data u64 (tag<<32|f32),
// double-buffered hbuf[2][H], relaxed agent-scope atomic stores, tag-gated
// consumption, LDS-only barriers. Round-9 changes (latency-surgical):
//   (1) 16 WGs instead of 32: halves poll fan-out per slot (r8 showed 4x
//       fan-out cost +1.2us/step -> contention is first-order) and halves
//       the producer tail.
//   (2) one u64 slot per thread -> poll = single dwordx2 + one tag compare.
//   (3) gx prefetch issued RIGHT AFTER poll success into double-buffered
//       regs (loop unrolled x2): the cold loads retire during compute+store,
//       so the next step's vmcnt(0) poll sample no longer inherits them
//       (in-order vmcnt retire, m135).
// Overwrite-safety induction (unchanged): WG o stores tag s+2 only after its
// 512 threads collectively saw ALL slots @ s+1, which certifies every WG
// (each consumer is a producer) finished consuming step s.
// ---------------------------------------------------------------------------
__global__ __launch_bounds__(512, 1) void gru_scan(
    const float* __restrict__ gx,
    const float* __restrict__ w_hh,
    const float* __restrict__ b_hh,
    const float* __restrict__ dec_w,
    const float* __restrict__ dec_b,
    const float* __restrict__ target,
    unsigned long long* __restrict__ hbuf,   // [2][H] (tag|value)
    float* __restrict__ out)
{
    __shared__ float h_lds[H];

    const int k   = blockIdx.x;
    const int tid = threadIdx.x;
    const int l   = tid & 15;    // lane within 16-lane group (column owner)
    const int g   = tid >> 4;    // group id 0..31
    const int i   = k * 32 + g;  // owned hidden index (this group's row)

    // Recurrent weights: rows i, H+i, 2H+i; cols 4l+64j+q (compiler remats
    // from L2 per step; measured faster than LDS staging, r3 vs r5).
    float4 wr[8], wz[8], wn[8];
    #pragma unroll
    for (int j = 0; j < 8; ++j) {
        const int c = 4 * l + 64 * j;
        wr[j] = *reinterpret_cast<const float4*>(w_hh + (size_t)i * H + c);
        wz[j] = *reinterpret_cast<const float4*>(w_hh + (size_t)(H + i) * H + c);
        wn[j] = *reinterpret_cast<const float4*>(w_hh + (size_t)(2 * H + i) * H + c);
    }
    const float bhr = b_hh[i], bhz = b_hh[H + i], bhn = b_hh[2 * H + i];

    // Double-buffered gx regs (lane 0 of each group only).
    float gxrA = 0.f, gxzA = 0.f, gxnA = 0.f;
    float gxrB = 0.f, gxzB = 0.f, gxnB = 0.f;
    if (l == 0) { gxrA = gx[i]; gxzA = gx[H + i]; gxnA = gx[2 * H + i]; }

#define GRU_STEP(S_, GR_, GZ_, GN_, GRN_, GZN_, GNN_)                         \
    {                                                                          \
        const int s_ = (S_);                                                   \
        if (s_ == 0) {                                                         \
            h_lds[tid] = 0.f;                                                  \
        } else {                                                               \
            const unsigned tg_ = (unsigned)s_;                                 \
            const unsigned long long* src_ =                                   \
                hbuf + (size_t)(s_ & 1) * H + tid;                             \
            unsigned long long v_ = ld2_mall(src_);                            \
            while ((unsigned)(v_ >> 32) != tg_) v_ = ld2_mall(src_);           \
            h_lds[tid] = __uint_as_float((unsigned)v_);                        \
        }                                                                      \
        if (l == 0) { /* prefetch gx for s+1; retires during compute */        \
            const int sn_ = (s_ + 1 < S) ? (s_ + 1) : (S - 1);                 \
            GRN_ = gx[(size_t)sn_ * G3 + i];                                   \
            GZN_ = gx[(size_t)sn_ * G3 + H + i];                               \
            GNN_ = gx[(size_t)sn_ * G3 + 2 * H + i];                           \
        }                                                                      \
        barrier_lds();                                                         \
        const float hp_ = h_lds[i];                                            \
        float ar = 0.f, az = 0.f, an = 0.f;                                    \
        _Pragma("unroll")                                                      \
        for (int j = 0; j < 8; ++j) {                                          \
            const float4 hv =                                                  \
                *reinterpret_cast<const float4*>(&h_lds[64 * j + 4 * l]);      \
            ar = fmaf(wr[j].x, hv.x, fmaf(wr[j].y, hv.y,                       \
                 fmaf(wr[j].z, hv.z, fmaf(wr[j].w, hv.w, ar))));               \
            az = fmaf(wz[j].x, hv.x, fmaf(wz[j].y, hv.y,                       \
                 fmaf(wz[j].z, hv.z, fmaf(wz[j].w, hv.w, az))));               \
            an = fmaf(wn[j].x, hv.x, fmaf(wn[j].y, hv.y,                       \
                 fmaf(wn[j].z, hv.z, fmaf(wn[j].w, hv.w, an))));               \
        }                                                                      \
        _Pragma("unroll")                                                      \
        for (int m = 8; m >= 1; m >>= 1) {                                     \
            ar += __shfl_xor(ar, m);                                           \
            az += __shfl_xor(az, m);                                           \
            an += __shfl_xor(an, m);                                           \
        }                                                                      \
        if (l == 0) {                                                          \
            const float r_  = 1.f / (1.f + __expf(-(GR_ + ar + bhr)));         \
            const float z_  = 1.f / (1.f + __expf(-(GZ_ + az + bhz)));         \
            const float nn_ = tanhf(GN_ + r_ * (an + bhn));                    \
            const float hnew_ = (1.f - z_) * nn_ + z_ * hp_;                   \
            const unsigned long long pv_ =                                     \
                ((unsigned long long)(unsigned)(s_ + 1) << 32) |               \
                (unsigned long long)__float_as_uint(hnew_);                    \
            __hip_atomic_store(hbuf + (size_t)((s_ + 1) & 1) * H + i, pv_,     \
                               __ATOMIC_RELAXED, __HIP_MEMORY_SCOPE_AGENT);    \
        }                                                                      \
        barrier_lds();                                                         \
    }

    for (int s = 0; s < S; s += 2) {
        GRU_STEP(s,     gxrA, gxzA, gxnA, gxrB, gxzB, gxnB);
        GRU_STEP(s + 1, gxrB, gxzB, gxnB, gxrA, gxzA, gxnA);
    }
#undef GRU_STEP

    // --- epilogue: WG0 gathers h_S (tag S, buffer 0) and computes BCE ---
    if (k == 0) {
        const unsigned tg = (unsigned)S;
        const unsigned long long* src = hbuf + tid;   // buffer (S&1)==0
        unsigned long long v = ld2_mall(src);
        while ((unsigned)(v >> 32) != tg) v = ld2_mall(src);
        h_lds[tid] = __uint_as_float((unsigned)v);
        __syncthreads();

        if (tid < 64) {
            float p = 0.f;
            #pragma unroll
            for (int j = 0; j < 8; ++j)
                p = fmaf(h_lds[tid + 64 * j], dec_w[tid + 64 * j], p);
            #pragma unroll
            for (int m = 32; m >= 1; m >>= 1) p += __shfl_xor(p, m);
            if (tid == 0) {
                const float xl = p + dec_b[0];
                const float t  = target[0];
                const float loss = fmaxf(xl, 0.f) - xl * t +
                                   log1pf(__expf(-fabsf(xl)));
                out[0] = loss;
            }
        }
    }
}

// ---------------------------------------------------------------------------
extern "C" void kernel_launch(void* const* d_in, const int* in_sizes, int n_in,
                              void* d_out, int out_size, void* d_ws, size_t ws_size,
                              hipStream_t stream) {
    const int*   x      = (const int*)d_in[0];
    const float* target = (const float*)d_in[1];
    const float* emb    = (const float*)d_in[2];
    const float* w_ih   = (const float*)d_in[3];
    const float* w_hh   = (const float*)d_in[4];
    const float* b_ih   = (const float*)d_in[5];
    const float* b_hh   = (const float*)d_in[6];
    const float* dec_w  = (const float*)d_in[7];
    const float* dec_b  = (const float*)d_in[8];
    float*       out    = (float*)d_out;

    float* gx = (float*)d_ws;                                   // [S][1536] = 25.2 MB
    unsigned long long* hbuf =
        (unsigned long long*)((char*)d_ws + (size_t)S * G3 * sizeof(float)); // [2][H]

    // Clear tags every launch so graph replays can't match stale tags.
    hipMemsetAsync(hbuf, 0, 2 * H * sizeof(unsigned long long), stream);

    gemm_gx<<<dim3(32 * 12), dim3(256), 0, stream>>>(x, emb, w_ih, b_ih, gx);
    gru_scan<<<dim3(NWG), dim3(512), 0, stream>>>(gx, w_hh, b_hh, dec_w, dec_b,
                                                  target, hbuf, out);
}